// Round 4
// baseline (3204.514 us; speedup 1.0000x reference)
//
#include <hip/hip_runtime.h>
#include <stdint.h>
#include <math.h>

// Problem constants (from reference)
constexpr int kB = 8;      // clouds
constexpr int kP = 8192;   // points per cloud
constexpr int kF = 32;     // feature dim
constexpr int kM = 2048;   // centroids per cloud (P * 0.25)
constexpr int kK = 64;     // max neighbors
constexpr int kH = 64;     // hidden dim
constexpr int kO = 128;    // output dim

// Exact-f32 squared distance matching numpy: square elementwise, then
// sequential sum ((dx2+dy2)+dz2). contract(off) forbids fma fusion so this
// matches numpy bit-for-bit regardless of -ffp-contract=fast default.
__device__ __forceinline__ float dist2(float ax, float ay, float az,
                                       float bx, float by, float bz) {
#pragma clang fp contract(off)
    float dx = ax - bx, dy = ay - by, dz = az - bz;
    return (dx * dx + dy * dy) + dz * dz;
}

// Fast variant for conservative bounds only (contraction allowed).
__device__ __forceinline__ float dist2_fast(float ax, float ay, float az,
                                            float bx, float by, float bz) {
    float dx = ax - bx, dy = ay - by, dz = az - bz;
    return dx * dx + dy * dy + dz * dz;
}

__device__ __forceinline__ unsigned int morton9(float x, float y, float z) {
    int ix = min(7, max(0, (int)(x * 8.0f)));
    int iy = min(7, max(0, (int)(y * 8.0f)));
    int iz = min(7, max(0, (int)(z * 8.0f)));
    auto sp = [](int v) {  // 3-bit spread: bits to positions 0,3,6
        return (v & 1) | ((v & 2) << 2) | ((v & 4) << 4);
    };
    return (sp(ix) << 2) | (sp(iy) << 1) | sp(iz);
}

// ---------------------------------------------------------------------------
// Kernel 1: farthest point sampling, exact with spatial pruning.
// One block (512 threads) per cloud. One-time: Morton counting sort so each
// thread owns 16 spatially-local points + bounding sphere (center, r).
// Per iteration, a thread whose whole sphere is provably farther from the
// new centroid than sqrt(max dd) (with 2e-3 abs margin >> f32 rounding)
// skips the 16-point update: dd/key provably unchanged -> bit-exact.
// Argmax key: (float_bits(d)<<32) | ~orig_idx -> u64 max == max-dist with
// lowest-original-index tie-break (numpy argmax first-occurrence).
// ---------------------------------------------------------------------------
__global__ __launch_bounds__(512) void fps_kernel(const float* __restrict__ pos,
                                                  float* __restrict__ cent_out) {
    const int b = blockIdx.x;
    const int tid = threadIdx.x;
    const float* pb = pos + (size_t)b * kP * 3;

    __shared__ float sxp[kP], syp[kP], szp[kP];   // SoA cloud copy (orig index)
    __shared__ unsigned short perm[kP];           // sorted slot -> orig idx
    __shared__ int cellcnt[512];
    __shared__ int ps[512];
    __shared__ unsigned long long part[2][8];     // ping-pong wave partials

    cellcnt[tid] = 0;

    // load cloud into LDS (coalesced), count Morton cells
    float tmpx[16], tmpy[16], tmpz[16];
#pragma unroll
    for (int q = 0; q < 16; ++q) {
        int i = tid + q * 512;
        tmpx[q] = pb[i * 3 + 0];
        tmpy[q] = pb[i * 3 + 1];
        tmpz[q] = pb[i * 3 + 2];
    }
    __syncthreads();   // cellcnt zeroed before atomics
#pragma unroll
    for (int q = 0; q < 16; ++q) {
        int i = tid + q * 512;
        sxp[i] = tmpx[q]; syp[i] = tmpy[q]; szp[i] = tmpz[q];
        atomicAdd(&cellcnt[morton9(tmpx[q], tmpy[q], tmpz[q])], 1);
    }
    __syncthreads();

    // exclusive prefix sum over 512 cells (Hillis-Steele)
    int v = cellcnt[tid];
    ps[tid] = v;
    __syncthreads();
    for (int d = 1; d < 512; d <<= 1) {
        int a = (tid >= d) ? ps[tid - d] : 0;
        __syncthreads();
        ps[tid] += a;
        __syncthreads();
    }
    cellcnt[tid] = ps[tid] - v;   // exclusive offset
    __syncthreads();

    // scatter: sorted order (intra-cell order non-deterministic; harmless —
    // keys use original indices and dd is per-point)
#pragma unroll
    for (int q = 0; q < 16; ++q) {
        int i = tid + q * 512;
        int slot = atomicAdd(&cellcnt[morton9(tmpx[q], tmpy[q], tmpz[q])], 1);
        perm[slot] = (unsigned short)i;
    }
    __syncthreads();

    // adopt owned 16 consecutive sorted points
    float px[16], py[16], pz[16], dd[16];
    unsigned int oidx[16];
#pragma unroll
    for (int q = 0; q < 16; ++q) {
        unsigned int o = perm[tid * 16 + q];
        oidx[q] = o;
        px[q] = sxp[o]; py[q] = syp[o]; pz[q] = szp[o];
        dd[q] = INFINITY;
    }
    // bounding sphere of owned points
    float mnx = px[0], mxx = px[0], mny = py[0], mxy = py[0], mnz = pz[0], mxz = pz[0];
#pragma unroll
    for (int q = 1; q < 16; ++q) {
        mnx = fminf(mnx, px[q]); mxx = fmaxf(mxx, px[q]);
        mny = fminf(mny, py[q]); mxy = fmaxf(mxy, py[q]);
        mnz = fminf(mnz, pz[q]); mxz = fmaxf(mxz, pz[q]);
    }
    float scx = 0.5f * (mnx + mxx), scy = 0.5f * (mny + mxy), scz = 0.5f * (mnz + mxz);
    float r2m = 0.0f;
#pragma unroll
    for (int q = 0; q < 16; ++q)
        r2m = fmaxf(r2m, dist2_fast(px[q], py[q], pz[q], scx, scy, scz));
    const float rad = sqrtf(r2m) * 1.0001f + 1e-5f;

    // first selected point: original index 0
    float lx = sxp[0], ly = syp[0], lz = szp[0];
    if (tid == 0) {
        cent_out[(size_t)(b * kM) * 3 + 0] = lx;
        cent_out[(size_t)(b * kM) * 3 + 1] = ly;
        cent_out[(size_t)(b * kM) * 3 + 2] = lz;
    }

    const int wave = tid >> 6, lane = tid & 63;
    unsigned long long key = 0ull;     // this thread's current best key
    float thresh = INFINITY;           // rad + sqrt(bv) + margin

    for (int m = 1; m < kM; ++m) {
        float d2c = dist2_fast(scx, scy, scz, lx, ly, lz);
        if (sqrtf(d2c) <= thresh) {
            // update path: refresh dd and thread-best key (exact math)
            unsigned long long k2 = 0ull;
#pragma unroll
            for (int q = 0; q < 16; ++q) {
                float d2 = dist2(px[q], py[q], pz[q], lx, ly, lz);
                float nd = fminf(dd[q], d2);
                dd[q] = nd;
                unsigned long long cand =
                    ((unsigned long long)__float_as_uint(nd) << 32) |
                    (unsigned int)(~oidx[q]);
                if (cand > k2) k2 = cand;
            }
            key = k2;
            float bv = __uint_as_float((unsigned int)(key >> 32));
            thresh = rad + sqrtf(bv) + 2e-3f;
        }

        // wave butterfly max on key (temp copy)
        unsigned long long rk = key;
#pragma unroll
        for (int off = 32; off >= 1; off >>= 1) {
            unsigned long long ok = __shfl_xor(rk, off, 64);
            if (ok > rk) rk = ok;
        }
        if (lane == 0) part[m & 1][wave] = rk;
        __syncthreads();

        unsigned long long k = part[m & 1][0];
#pragma unroll
        for (int w = 1; w < 8; ++w) {
            unsigned long long o = part[m & 1][w];
            if (o > k) k = o;
        }
        unsigned int wi = ~(unsigned int)k;        // recover original index
        lx = sxp[wi]; ly = syp[wi]; lz = szp[wi];  // broadcast reads

        if (tid == 0) {
            size_t o = (size_t)(b * kM + m) * 3;
            cent_out[o + 0] = lx;
            cent_out[o + 1] = ly;
            cent_out[o + 2] = lz;
        }
        // ping-pong part[] + next barrier order the WAR hazard
    }
}

// ---------------------------------------------------------------------------
// Kernel 2: radius ball query. One wave per centroid (4 waves / 256-thread
// block). Scan points in index order 64 at a time; ballot + prefix popcount
// assigns output slots -> lowest indices first, exactly like the reference's
// sort+take-K. Early exit once K neighbors found.
// ---------------------------------------------------------------------------
__global__ __launch_bounds__(256) void ball_kernel(const float* __restrict__ pos,
                                                   const float* __restrict__ cent,
                                                   uint16_t* __restrict__ nb,
                                                   int* __restrict__ cnt_arr,
                                                   float* __restrict__ batch_out) {
    const int wave = threadIdx.x >> 6, lane = threadIdx.x & 63;
    const int c = blockIdx.x * 4 + wave;
    const int b = c >> 11;  // c / kM
    const float R2 = (float)(0.2 * 0.2);  // same double->float rounding as reference

    float cx = cent[(size_t)c * 3 + 0];
    float cy = cent[(size_t)c * 3 + 1];
    float cz = cent[(size_t)c * 3 + 2];
    const float* pb = pos + (size_t)b * kP * 3;

    int cnt = 0;
    for (int p0 = 0; p0 < kP && cnt < kK; p0 += 64) {
        int i = p0 + lane;
        float x = pb[i * 3 + 0], y = pb[i * 3 + 1], z = pb[i * 3 + 2];
        float d2 = dist2(x, y, z, cx, cy, cz);
        bool in = d2 <= R2;
        unsigned long long mask = __ballot(in);
        int rank = __popcll(mask & ((1ull << lane) - 1ull));
        if (in && cnt + rank < kK) {
            nb[(size_t)c * kK + cnt + rank] = (uint16_t)i;
        }
        cnt = min(cnt + (int)__popcll(mask), kK);
    }
    if (lane == 0) {
        cnt_arr[c] = cnt;
        batch_out[c] = (float)b;
    }
}

// ---------------------------------------------------------------------------
// Kernel 3: gather -> MLP (35->64->64->128, ReLU) -> masked max over K.
// One block (256 threads) per centroid. msg/h1/h2 staged in LDS; each thread
// holds its weight column in registers; LDS reads are same-address broadcast.
// ---------------------------------------------------------------------------
__global__ __launch_bounds__(256) void mlp_kernel(const float* __restrict__ pos,
                                                  const float* __restrict__ x,
                                                  const float* __restrict__ cent,
                                                  const uint16_t* __restrict__ nb,
                                                  const int* __restrict__ cnt_arr,
                                                  const float* __restrict__ W1,
                                                  const float* __restrict__ b1,
                                                  const float* __restrict__ W2,
                                                  const float* __restrict__ b2,
                                                  const float* __restrict__ W3,
                                                  const float* __restrict__ b3,
                                                  float* __restrict__ feat_out) {
    const int c = blockIdx.x;
    const int b = c >> 11;
    const int tid = threadIdx.x;

    __shared__ float msg[kK][36];     // 35 used, stride 36
    __shared__ float h1[kK][kH];
    __shared__ float h2[kK][kH];
    __shared__ float s_cent[3];
    __shared__ int s_nb[kK];
    __shared__ int s_cnt;
    __shared__ float red[2][kO];

    if (tid < kK) s_nb[tid] = nb[(size_t)c * kK + tid];
    if (tid == 0) s_cnt = cnt_arr[c];
    if (tid < 3) s_cent[tid] = cent[(size_t)c * 3 + tid];
    __syncthreads();
    const int cnt = s_cnt;

    // gather msg = [x_j (32) | pos_j - cent (3)]
    for (int u = tid; u < kK * 35; u += 256) {
        int k = u / 35, f = u - k * 35;
        float v = 0.0f;
        if (k < cnt) {
            int n = s_nb[k];
            if (f < 32) v = x[((size_t)b * kP + n) * kF + f];
            else        v = pos[((size_t)b * kP + n) * 3 + (f - 32)] - s_cent[f - 32];
        }
        msg[k][f] = v;
    }
    __syncthreads();

    // layer 1: 35 -> 64
    {
        int j = tid & 63, k0 = tid >> 6;  // k0 in [0,4)
        float w[35];
#pragma unroll
        for (int i = 0; i < 35; ++i) w[i] = W1[i * 64 + j];
        float bb = b1[j];
#pragma unroll
        for (int kk = 0; kk < 16; ++kk) {
            int k = k0 * 16 + kk;
            float acc = bb;
#pragma unroll
            for (int i = 0; i < 35; ++i) acc += msg[k][i] * w[i];
            h1[k][j] = fmaxf(acc, 0.0f);
        }
    }
    __syncthreads();

    // layer 2: 64 -> 64
    {
        int j = tid & 63, k0 = tid >> 6;
        float w[64];
#pragma unroll
        for (int i = 0; i < 64; ++i) w[i] = W2[i * 64 + j];
        float bb = b2[j];
#pragma unroll
        for (int kk = 0; kk < 16; ++kk) {
            int k = k0 * 16 + kk;
            float acc = bb;
#pragma unroll
            for (int i = 0; i < 64; ++i) acc += h1[k][i] * w[i];
            h2[k][j] = fmaxf(acc, 0.0f);
        }
    }
    __syncthreads();

    // layer 3: 64 -> 128, fused masked max over valid k
    {
        int j = tid & 127, k0 = tid >> 7;  // k0 in {0,1}
        float w[64];
#pragma unroll
        for (int i = 0; i < 64; ++i) w[i] = W3[i * 128 + j];
        float bb = b3[j];
        float best = -INFINITY;
        for (int kk = 0; kk < 32; ++kk) {
            int k = k0 * 32 + kk;      // wave-uniform bound
            if (k >= cnt) break;
            float acc = bb;
#pragma unroll
            for (int i = 0; i < 64; ++i) acc += h2[k][i] * w[i];
            best = fmaxf(best, fmaxf(acc, 0.0f));
        }
        red[k0][j] = best;
    }
    __syncthreads();

    if (tid < kO) {
        float o = fmaxf(red[0][tid], red[1][tid]);  // cnt>=1 -> red[0] valid
        feat_out[(size_t)c * kO + tid] = o;
    }
}

// ---------------------------------------------------------------------------
extern "C" void kernel_launch(void* const* d_in, const int* in_sizes, int n_in,
                              void* d_out, int out_size, void* d_ws, size_t ws_size,
                              hipStream_t stream) {
    const float* pos = (const float*)d_in[0];
    // d_in[1] = batch (unused; implied by layout)
    const float* x  = (const float*)d_in[2];
    const float* W1 = (const float*)d_in[3];
    const float* b1 = (const float*)d_in[4];
    const float* W2 = (const float*)d_in[5];
    const float* b2 = (const float*)d_in[6];
    const float* W3 = (const float*)d_in[7];
    const float* b3 = (const float*)d_in[8];

    float* out = (float*)d_out;
    float* cent_out  = out;                                   // [B*M, 3]
    float* feat_out  = out + (size_t)kB * kM * 3;             // [B*M, 128]
    float* batch_out = out + (size_t)kB * kM * (3 + kO);      // [B*M]

    char* ws = (char*)d_ws;
    int* cnt_arr   = (int*)ws;                                // B*M ints
    uint16_t* nbuf = (uint16_t*)(ws + (size_t)kB * kM * 4);   // B*M*K u16

    fps_kernel<<<kB, 512, 0, stream>>>(pos, cent_out);
    ball_kernel<<<(kB * kM) / 4, 256, 0, stream>>>(pos, cent_out, nbuf, cnt_arr, batch_out);
    mlp_kernel<<<kB * kM, 256, 0, stream>>>(pos, x, cent_out, nbuf, cnt_arr,
                                            W1, b1, W2, b2, W3, b3, feat_out);
}